// Round 1
// baseline (210.889 us; speedup 1.0000x reference)
//
#include <hip/hip_runtime.h>
#include <hip/hip_bf16.h>
#include <stdint.h>

// B=8, T=64, N=128, FIN=64, D=64, LAG=8
// rows (b,t,n) flattened: 65536 rows of 64 features.

typedef __bf16 bf16x8 __attribute__((ext_vector_type(8)));
typedef float f32x4 __attribute__((ext_vector_type(4)));

#define MFMA16(a, b, c) __builtin_amdgcn_mfma_f32_16x16x32_bf16((a), (b), (c), 0, 0, 0)

__device__ __forceinline__ unsigned short f2bf(float f) {
    union { float f; unsigned u; } v; v.f = f;
    unsigned r = v.u + 0x7FFFu + ((v.u >> 16) & 1u);
    return (unsigned short)(r >> 16);
}
__device__ __forceinline__ float bf2f(unsigned short h) {
    union { unsigned u; float f; } v; v.u = ((unsigned)h) << 16;
    return v.f;
}
__device__ __forceinline__ f32x4 fzero4() {
    f32x4 z; z[0] = 0.f; z[1] = 0.f; z[2] = 0.f; z[3] = 0.f; return z;
}

// ---------------------------------------------------------------------------
// Kernel 1: fused QKV projection. Vector fp32 GEMM with 8x12 register tiles.
// Block: 256 threads, 128 rows (one (b,t)). Grid: 512.
// Outputs Q,K,V as bf16 row-major [65536][64] into workspace.
// ---------------------------------------------------------------------------
__global__ __launch_bounds__(256) void qkv_kernel(
    const float* __restrict__ X,
    const float* __restrict__ Wq, const float* __restrict__ bq,
    const float* __restrict__ Wk, const float* __restrict__ bk,
    const float* __restrict__ Wv, const float* __restrict__ bv,
    unsigned short* __restrict__ Qo, unsigned short* __restrict__ Ko,
    unsigned short* __restrict__ Vo)
{
    __shared__ float Xs[128][66];            // +2 pad: conflict-free row reads
    __shared__ unsigned short Ws[64][192];   // [k][c] c: 0..63 Wq, 64..127 Wk, 128..191 Wv (bf16)

    const int tid = threadIdx.x;
    const size_t row0 = (size_t)blockIdx.x * 128;

    for (int i = tid; i < 8192; i += 256) {  // X tile: 128x64 fp32
        int r = i >> 6, c = i & 63;
        Xs[r][c] = X[row0 * 64 + i];
    }
    for (int i = tid; i < 4096; i += 256) {  // weights (bf16 in LDS)
        int k = i >> 6, c = i & 63;
        Ws[k][c]       = f2bf(Wq[i]);
        Ws[k][c + 64]  = f2bf(Wk[i]);
        Ws[k][c + 128] = f2bf(Wv[i]);
    }
    __syncthreads();

    const int cL = tid & 15;           // 16 col-lanes, cols cL + 16j (coalesced stores)
    const int r0 = (tid >> 4) * 8;     // 8 rows per thread

    float acc[8][12];
#pragma unroll
    for (int i = 0; i < 8; ++i)
#pragma unroll
        for (int j = 0; j < 12; ++j) acc[i][j] = 0.f;

    for (int k = 0; k < 64; ++k) {
        float x[8];
#pragma unroll
        for (int i = 0; i < 8; ++i) x[i] = Xs[r0 + i][k];
#pragma unroll
        for (int j = 0; j < 12; ++j) {
            float w = bf2f(Ws[k][cL + 16 * j]);
#pragma unroll
            for (int i = 0; i < 8; ++i) acc[i][j] += x[i] * w;
        }
    }

#pragma unroll
    for (int j = 0; j < 12; ++j) {
        int c = cL + 16 * j;
        int which = c >> 6, d = c & 63;
        const float* bias = (which == 0) ? bq : (which == 1) ? bk : bv;
        unsigned short* out = (which == 0) ? Qo : (which == 1) ? Ko : Vo;
        float b = bias[d];
#pragma unroll
        for (int i = 0; i < 8; ++i) {
            float v = acc[i][j] + b;
            v = v > 0.f ? v : 0.f;
            out[(row0 + r0 + i) * 64 + d] = f2bf(v);
        }
    }
}

// ---------------------------------------------------------------------------
// Kernel 2: fused lag-window attention + output projection.
// One block per (b,t): 4 waves, wave w owns query rows w*32..w*32+31.
// Online softmax over 8 lag chunks of 128 keys each; zero-padded lags
// folded in analytically at the end. LDS tiles XOR-swizzled (^ (row&7)<<4)
// so all MFMA fragment reads are conflict-free ds_read_b128.
// ---------------------------------------------------------------------------
__global__ __launch_bounds__(256) void attn_kernel(
    const unsigned short* __restrict__ Qg,
    const unsigned short* __restrict__ Kg,
    const unsigned short* __restrict__ Vg,
    const float* __restrict__ Wo,
    const float* __restrict__ bo,
    float* __restrict__ Out)
{
    __shared__ unsigned char ldsK[16384];  // K chunk [128 keys][64 d] bf16; later Wo^T [64][128]
    __shared__ unsigned char ldsV[16384];  // V^T chunk [64 d][128 keys] bf16
    __shared__ unsigned char ldsP[32768];  // P [128 q][128 keys] bf16; later agg [128 q][64 d]

    const int tid  = threadIdx.x;
    const int lane = tid & 63;
    const int wv   = tid >> 6;
    const int cl   = lane & 15;
    const int g    = lane >> 4;
    const int bt   = blockIdx.x;       // b*64 + t
    const int t    = bt & 63;
    const int qr0  = wv * 32;

    // Q A-fragments, straight from global (also reused as h[:, 0:64] at the end)
    bf16x8 aq[2][2];
#pragma unroll
    for (int mi = 0; mi < 2; ++mi)
#pragma unroll
        for (int kk = 0; kk < 2; ++kk) {
            size_t r = (size_t)bt * 128 + qr0 + mi * 16 + cl;
            aq[mi][kk] = *(const bf16x8*)(Qg + r * 64 + kk * 32 + g * 8);
        }

    f32x4 o[2][4];
    float m[2][4], lsum[2][4];
#pragma unroll
    for (int mi = 0; mi < 2; ++mi) {
#pragma unroll
        for (int ni = 0; ni < 4; ++ni) o[mi][ni] = fzero4();
#pragma unroll
        for (int r = 0; r < 4; ++r) { m[mi][r] = -1e30f; lsum[mi][r] = 0.f; }
    }

    for (int lg = 0; lg < 8; ++lg) {
        int st = t - 7 + lg;           // source time (block-uniform)
        if (st < 0) continue;
        __syncthreads();               // previous chunk fully consumed
        {   // stage K chunk (swizzled) and V chunk transposed (swizzled)
            const size_t base = (size_t)(bt - (7 - lg)) * 128 * 64;
            int r  = tid >> 1;                 // key row 0..127
            int c0 = (tid & 1) * 32;           // d half
            const unsigned short* ksrc = Kg + base + r * 64 + c0;
            const unsigned short* vsrc = Vg + base + r * 64 + c0;
#pragma unroll
            for (int s = 0; s < 4; ++s) {
                uint4 kv = *(const uint4*)(ksrc + s * 8);
                int byte = (r * 128 + (c0 + s * 8) * 2) ^ ((r & 7) << 4);
                *(uint4*)(ldsK + byte) = kv;
            }
#pragma unroll
            for (int s = 0; s < 4; ++s) {
                uint4 vv = *(const uint4*)(vsrc + s * 8);
                const unsigned short* pv = (const unsigned short*)&vv;
#pragma unroll
                for (int j = 0; j < 8; ++j) {
                    int d = c0 + s * 8 + j;
                    int byte = (d * 256 + r * 2) ^ ((d & 7) << 4);
                    *(unsigned short*)(ldsV + byte) = pv[j];
                }
            }
        }
        __syncthreads();

        // S = Q K^T (fp32 acc), rows=query, cols=key
        f32x4 s[2][8];
#pragma unroll
        for (int mi = 0; mi < 2; ++mi)
#pragma unroll
            for (int ki = 0; ki < 8; ++ki) s[mi][ki] = fzero4();
#pragma unroll
        for (int ki = 0; ki < 8; ++ki) {
            int krow = ki * 16 + cl;
#pragma unroll
            for (int kk = 0; kk < 2; ++kk) {
                int byte = (krow * 128 + kk * 64 + g * 16) ^ ((krow & 7) << 4);
                bf16x8 bk_ = *(const bf16x8*)(ldsK + byte);
                s[0][ki] = MFMA16(aq[0][kk], bk_, s[0][ki]);
                s[1][ki] = MFMA16(aq[1][kk], bk_, s[1][ki]);
            }
        }

        // online softmax update (16 lanes of a col-group share the same rows)
#pragma unroll
        for (int mi = 0; mi < 2; ++mi)
#pragma unroll
            for (int r = 0; r < 4; ++r) {
                float mx = -1e30f;
#pragma unroll
                for (int ki = 0; ki < 8; ++ki) {
                    float v = s[mi][ki][r] * 0.125f;   // 1/sqrt(D)
                    s[mi][ki][r] = v;
                    mx = fmaxf(mx, v);
                }
#pragma unroll
                for (int sh = 1; sh <= 8; sh <<= 1) mx = fmaxf(mx, __shfl_xor(mx, sh, 64));
                float mn = fmaxf(m[mi][r], mx);
                float f  = __expf(m[mi][r] - mn);
                float rs = 0.f;
#pragma unroll
                for (int ki = 0; ki < 8; ++ki) {
                    float p = __expf(s[mi][ki][r] - mn);
                    s[mi][ki][r] = p;
                    rs += p;
                }
#pragma unroll
                for (int sh = 1; sh <= 8; sh <<= 1) rs += __shfl_xor(rs, sh, 64);
                lsum[mi][r] = lsum[mi][r] * f + rs;
                m[mi][r] = mn;
#pragma unroll
                for (int ni = 0; ni < 4; ++ni) o[mi][ni][r] *= f;
            }

        // P -> LDS (bf16, own-wave rows only; no barrier needed)
#pragma unroll
        for (int mi = 0; mi < 2; ++mi)
#pragma unroll
            for (int ki = 0; ki < 8; ++ki)
#pragma unroll
                for (int r = 0; r < 4; ++r) {
                    int row = qr0 + mi * 16 + g * 4 + r;
                    int col = ki * 16 + cl;
                    int byte = (row * 256 + col * 2) ^ ((row & 7) << 4);
                    *(unsigned short*)(ldsP + byte) = f2bf(s[mi][ki][r]);
                }

        // O += P V
#pragma unroll
        for (int kk2 = 0; kk2 < 4; ++kk2) {
            bf16x8 pa[2];
#pragma unroll
            for (int mi = 0; mi < 2; ++mi) {
                int row = qr0 + mi * 16 + cl;
                int byte = (row * 256 + kk2 * 64 + g * 16) ^ ((row & 7) << 4);
                pa[mi] = *(const bf16x8*)(ldsP + byte);
            }
#pragma unroll
            for (int ni = 0; ni < 4; ++ni) {
                int d = ni * 16 + cl;
                int byte = (d * 256 + kk2 * 64 + g * 16) ^ ((d & 7) << 4);
                bf16x8 bv_ = *(const bf16x8*)(ldsV + byte);
                o[0][ni] = MFMA16(pa[0], bv_, o[0][ni]);
                o[1][ni] = MFMA16(pa[1], bv_, o[1][ni]);
            }
        }
    }

    // padded lags (t-l < 0) have score exactly 0 for all 128 keys: fold in.
    if (t < 7) {
        float npad = 128.0f * (float)(7 - t);
#pragma unroll
        for (int mi = 0; mi < 2; ++mi)
#pragma unroll
            for (int r = 0; r < 4; ++r) {
                float mn = fmaxf(m[mi][r], 0.f);
                float f  = __expf(m[mi][r] - mn);
                lsum[mi][r] = lsum[mi][r] * f + npad * __expf(-mn);
#pragma unroll
                for (int ni = 0; ni < 4; ++ni) o[mi][ni][r] *= f;
            }
    }

    __syncthreads();  // everyone done reading P/V

    // agg = O / lsum -> ldsP as [128][64] bf16 (swizzled)
#pragma unroll
    for (int mi = 0; mi < 2; ++mi)
#pragma unroll
        for (int ni = 0; ni < 4; ++ni)
#pragma unroll
            for (int r = 0; r < 4; ++r) {
                int row = qr0 + mi * 16 + g * 4 + r;
                int d = ni * 16 + cl;
                int byte = (row * 128 + d * 2) ^ ((row & 7) << 4);
                *(unsigned short*)(ldsP + byte) = f2bf(o[mi][ni][r] / lsum[mi][r]);
            }

    __syncthreads();  // before overwriting ldsK with Wo^T
    for (int i = tid; i < 8192; i += 256) {   // Wo^T: [dout 0..63][c 0..127]
        int c = i >> 6, n = i & 63;
        int byte = (n * 256 + c * 2) ^ ((n & 7) << 4);
        *(unsigned short*)(ldsK + byte) = f2bf(Wo[i]);
    }
    __syncthreads();

    // out = relu([Q | agg] @ Wo + bo)
    f32x4 ho[2][4];
#pragma unroll
    for (int mi = 0; mi < 2; ++mi)
#pragma unroll
        for (int ni = 0; ni < 4; ++ni) ho[mi][ni] = fzero4();
#pragma unroll
    for (int kk = 0; kk < 4; ++kk) {
        bf16x8 ha[2];
        if (kk < 2) {
            ha[0] = aq[0][kk];
            ha[1] = aq[1][kk];
        } else {
#pragma unroll
            for (int mi = 0; mi < 2; ++mi) {
                int row = qr0 + mi * 16 + cl;
                int byte = (row * 128 + (kk - 2) * 64 + g * 16) ^ ((row & 7) << 4);
                ha[mi] = *(const bf16x8*)(ldsP + byte);
            }
        }
#pragma unroll
        for (int ni = 0; ni < 4; ++ni) {
            int n = ni * 16 + cl;
            int byte = (n * 256 + kk * 64 + g * 16) ^ ((n & 7) << 4);
            bf16x8 wb = *(const bf16x8*)(ldsK + byte);
            ho[0][ni] = MFMA16(ha[0], wb, ho[0][ni]);
            ho[1][ni] = MFMA16(ha[1], wb, ho[1][ni]);
        }
    }
#pragma unroll
    for (int ni = 0; ni < 4; ++ni) {
        float b = bo[ni * 16 + cl];
#pragma unroll
        for (int mi = 0; mi < 2; ++mi)
#pragma unroll
            for (int r = 0; r < 4; ++r) {
                float v = ho[mi][ni][r] + b;
                v = v > 0.f ? v : 0.f;
                size_t row = (size_t)bt * 128 + qr0 + mi * 16 + g * 4 + r;
                Out[row * 64 + ni * 16 + cl] = v;
            }
    }
}

// ---------------------------------------------------------------------------
extern "C" void kernel_launch(void* const* d_in, const int* in_sizes, int n_in,
                              void* d_out, int out_size, void* d_ws, size_t ws_size,
                              hipStream_t stream) {
    const float* X  = (const float*)d_in[0];
    const float* Wq = (const float*)d_in[1];
    const float* bq = (const float*)d_in[2];
    const float* Wk = (const float*)d_in[3];
    const float* bk = (const float*)d_in[4];
    const float* Wv = (const float*)d_in[5];
    const float* bv = (const float*)d_in[6];
    const float* Wo = (const float*)d_in[7];
    const float* bo = (const float*)d_in[8];
    float* Out = (float*)d_out;

    unsigned short* Qw = (unsigned short*)d_ws;            // 3 x 8MB bf16 in workspace
    unsigned short* Kw = Qw + (size_t)65536 * 64;
    unsigned short* Vw = Kw + (size_t)65536 * 64;

    hipLaunchKernelGGL(qkv_kernel, dim3(512), dim3(256), 0, stream,
                       X, Wq, bq, Wk, bk, Wv, bv, Qw, Kw, Vw);
    hipLaunchKernelGGL(attn_kernel, dim3(512), dim3(256), 0, stream,
                       Qw, Kw, Vw, Wo, bo, Out);
}

// Round 2
// 153.392 us; speedup vs baseline: 1.3748x; 1.3748x over previous
//
#include <hip/hip_runtime.h>
#include <stdint.h>

// B=8, T=64, N=128, FIN=64, D=64, LAG=8.  Rows (b,t,n): 65536 x 64.

typedef __bf16 bf16x8 __attribute__((ext_vector_type(8)));
typedef float f32x4 __attribute__((ext_vector_type(4)));

#define MFMA16(a, b, c) __builtin_amdgcn_mfma_f32_16x16x32_bf16((a), (b), (c), 0, 0, 0)

__device__ __forceinline__ unsigned short f2bf(float f) {
    union { float f; unsigned u; } v; v.f = f;
    unsigned r = v.u + 0x7FFFu + ((v.u >> 16) & 1u);
    return (unsigned short)(r >> 16);
}
__device__ __forceinline__ unsigned cvtpk(float lo, float hi) {
    unsigned r;
    asm("v_cvt_pk_bf16_f32 %0, %1, %2" : "=v"(r) : "v"(lo), "v"(hi));
    return r;
}
__device__ __forceinline__ f32x4 fzero4() {
    f32x4 z; z[0] = 0.f; z[1] = 0.f; z[2] = 0.f; z[3] = 0.f; return z;
}

// ---------------------------------------------------------------------------
// Kernel 1: QKV projection via MFMA. Grid 1024 x 256 threads (4 waves x 16 rows).
// Computes Q,K in transposed orientation D[c][n] -> packed 8B row-major stores;
// V in normal orientation D[n][d] -> packed 8B stores of V^T[bt][d][n].
// ---------------------------------------------------------------------------
__global__ __launch_bounds__(256) void qkv_kernel(
    const float* __restrict__ X,
    const float* __restrict__ Wq, const float* __restrict__ bq,
    const float* __restrict__ Wk, const float* __restrict__ bk,
    const float* __restrict__ Wv, const float* __restrict__ bv,
    unsigned short* __restrict__ Qo, unsigned short* __restrict__ Ko,
    unsigned short* __restrict__ Vt)
{
    // W^T bf16 [192 c][64 f], XOR-swizzled. c: 0-63 Wq, 64-127 Wk, 128-191 Wv.
    __shared__ __align__(16) unsigned short WTl[192 * 64];
    unsigned char* wtb = (unsigned char*)WTl;

    const int tid = threadIdx.x;
    // stage W^T (coalesced global reads; 8-way LDS write conflicts acceptable, one-time)
    for (int i = tid; i < 4096; i += 256) {
        int f = i >> 6, c = i & 63;
        float wq_ = Wq[f * 64 + c], wk_ = Wk[f * 64 + c], wv_ = Wv[f * 64 + c];
        int c0 = c,        b0 = (c0 * 128 + f * 2) ^ ((c0 & 7) << 4);
        int c1 = c + 64,   b1 = (c1 * 128 + f * 2) ^ ((c1 & 7) << 4);
        int c2 = c + 128,  b2 = (c2 * 128 + f * 2) ^ ((c2 & 7) << 4);
        *(unsigned short*)(wtb + b0) = f2bf(wq_);
        *(unsigned short*)(wtb + b1) = f2bf(wk_);
        *(unsigned short*)(wtb + b2) = f2bf(wv_);
    }
    __syncthreads();

    const int lane = tid & 63, wv_id = tid >> 6;
    const int cl = lane & 15, g = lane >> 4;
    const size_t row0 = (size_t)blockIdx.x * 64 + wv_id * 16;  // 16 rows per wave
    const int bt = (int)(row0 >> 7);
    const int nb = (int)(row0 & 127);          // n-base of this wave within its (b,t)

    // X fragments: lane: X[row0+cl][kk*32 + g*8 .. +7], fp32 -> bf16
    bf16x8 xf[2];
    {
        const float* xp = X + (row0 + cl) * 64;
#pragma unroll
        for (int kk = 0; kk < 2; ++kk) {
            float4 a = *(const float4*)(xp + kk * 32 + g * 8);
            float4 b = *(const float4*)(xp + kk * 32 + g * 8 + 4);
            unsigned u[4];
            u[0] = cvtpk(a.x, a.y); u[1] = cvtpk(a.z, a.w);
            u[2] = cvtpk(b.x, b.y); u[3] = cvtpk(b.z, b.w);
            xf[kk] = *(bf16x8*)u;
        }
    }

    f32x4 accq[4], acck[4], accv[4];
#pragma unroll
    for (int i = 0; i < 4; ++i) { accq[i] = fzero4(); acck[i] = fzero4(); accv[i] = fzero4(); }

#pragma unroll
    for (int kk = 0; kk < 2; ++kk) {
#pragma unroll
        for (int dt = 0; dt < 4; ++dt) {
            int cq = dt * 16 + cl;
            bf16x8 wqf = *(const bf16x8*)(wtb + ((cq * 128 + (kk * 32 + g * 8) * 2) ^ ((cq & 7) << 4)));
            accq[dt] = MFMA16(wqf, xf[kk], accq[dt]);
            int ck = 64 + dt * 16 + cl;
            bf16x8 wkf = *(const bf16x8*)(wtb + ((ck * 128 + (kk * 32 + g * 8) * 2) ^ ((ck & 7) << 4)));
            acck[dt] = MFMA16(wkf, xf[kk], acck[dt]);
            int cv = 128 + dt * 16 + cl;
            bf16x8 wvf = *(const bf16x8*)(wtb + ((cv * 128 + (kk * 32 + g * 8) * 2) ^ ((cv & 7) << 4)));
            accv[dt] = MFMA16(xf[kk], wvf, accv[dt]);
        }
    }

#pragma unroll
    for (int dt = 0; dt < 4; ++dt) {
        // Q, K: D[c][n]: lane holds col n=row0+cl, rows c = dt*16+g*4+r (consecutive)
        float q0 = fmaxf(accq[dt][0] + bq[dt * 16 + g * 4 + 0], 0.f);
        float q1 = fmaxf(accq[dt][1] + bq[dt * 16 + g * 4 + 1], 0.f);
        float q2 = fmaxf(accq[dt][2] + bq[dt * 16 + g * 4 + 2], 0.f);
        float q3 = fmaxf(accq[dt][3] + bq[dt * 16 + g * 4 + 3], 0.f);
        uint2 qp; qp.x = cvtpk(q0, q1); qp.y = cvtpk(q2, q3);
        *(uint2*)(Qo + (row0 + cl) * 64 + dt * 16 + g * 4) = qp;

        float k0 = fmaxf(acck[dt][0] + bk[dt * 16 + g * 4 + 0], 0.f);
        float k1 = fmaxf(acck[dt][1] + bk[dt * 16 + g * 4 + 1], 0.f);
        float k2 = fmaxf(acck[dt][2] + bk[dt * 16 + g * 4 + 2], 0.f);
        float k3 = fmaxf(acck[dt][3] + bk[dt * 16 + g * 4 + 3], 0.f);
        uint2 kp; kp.x = cvtpk(k0, k1); kp.y = cvtpk(k2, k3);
        *(uint2*)(Ko + (row0 + cl) * 64 + dt * 16 + g * 4) = kp;

        // V: D[n][d]: lane holds col d=dt*16+cl, rows n = nb+g*4+r (consecutive)
        int d = dt * 16 + cl;
        float bvv = bv[d];
        float v0 = fmaxf(accv[dt][0] + bvv, 0.f);
        float v1 = fmaxf(accv[dt][1] + bvv, 0.f);
        float v2 = fmaxf(accv[dt][2] + bvv, 0.f);
        float v3 = fmaxf(accv[dt][3] + bvv, 0.f);
        uint2 vp; vp.x = cvtpk(v0, v1); vp.y = cvtpk(v2, v3);
        *(uint2*)(Vt + (size_t)bt * 8192 + d * 128 + nb + g * 4) = vp;
    }
}

// ---------------------------------------------------------------------------
// Kernel 2: lag attention + output projection. Grid 512 x 512 threads (8 waves
// x 16 queries). Swapped-operand QK^T, no max-tracking softmax, register
// prefetch of next chunk, XCD-chunked block swizzle.
// ---------------------------------------------------------------------------
__global__ __launch_bounds__(512, 4) void attn_kernel(
    const unsigned short* __restrict__ Qg,
    const unsigned short* __restrict__ Kg,
    const unsigned short* __restrict__ Vt,
    const float* __restrict__ Wo,
    const float* __restrict__ bo,
    float* __restrict__ Out)
{
    __shared__ __align__(16) unsigned char ldsK[16384];  // K [128key][64d]; later h(agg) [128q][64c]
    __shared__ __align__(16) unsigned char ldsV[16384];  // V^T [64d][128key]; later Wo^T [64][128]
    __shared__ __align__(16) unsigned char ldsP[32768];  // P [128q][128key] bf16 (per-wave regions)
    __shared__ float lsumBuf[128];

    const int tid = threadIdx.x;
    const int lane = tid & 63, wv = tid >> 6;
    const int cl = lane & 15, g = lane >> 4;
    const int bid = blockIdx.x;
    const int bt = (bid & 7) * 64 + (bid >> 3);   // XCD-chunked swizzle (512 % 8 == 0)
    const int t = bt & 63;
    const int wq0 = wv * 16;

    // Q fragments (B-operand of S^T; A-operand of out-proj)
    bf16x8 qf[2];
    {
        const unsigned short* qp = Qg + ((size_t)bt * 128 + wq0 + cl) * 64;
        qf[0] = *(const bf16x8*)(qp + g * 8);
        qf[1] = *(const bf16x8*)(qp + 32 + g * 8);
    }

    f32x4 o[4];
#pragma unroll
    for (int ni = 0; ni < 4; ++ni) o[ni] = fzero4();
    float lsum = 0.f;

    const int lg0 = (t < 7) ? (7 - t) : 0;

    uint4 kreg[2], vreg[2];
    {
        const uint4* kp = (const uint4*)(Kg + (size_t)(bt - 7 + lg0) * 8192);
        const uint4* vp = (const uint4*)(Vt + (size_t)(bt - 7 + lg0) * 8192);
        kreg[0] = kp[tid]; kreg[1] = kp[tid + 512];
        vreg[0] = vp[tid]; vreg[1] = vp[tid + 512];
    }

    for (int lg = lg0; lg < 8; ++lg) {
        __syncthreads();   // previous chunk fully consumed
        {   // staged regs -> LDS (swizzled, vector b128 writes)
#pragma unroll
            for (int j = 0; j < 2; ++j) {
                int i = tid + j * 512;
                int key = i >> 3, d0 = (i & 7) * 8;
                *(uint4*)(ldsK + ((key * 128 + d0 * 2) ^ ((key & 7) << 4))) = kreg[j];
                int d = i >> 4, n0 = (i & 15) * 8;
                *(uint4*)(ldsV + ((d * 256 + n0 * 2) ^ ((d & 7) << 4))) = vreg[j];
            }
        }
        if (lg < 7) {   // prefetch next chunk (in flight across the compute below)
            const uint4* kp = (const uint4*)(Kg + (size_t)(bt - 6 + lg) * 8192);
            const uint4* vp = (const uint4*)(Vt + (size_t)(bt - 6 + lg) * 8192);
            kreg[0] = kp[tid]; kreg[1] = kp[tid + 512];
            vreg[0] = vp[tid]; vreg[1] = vp[tid + 512];
        }
        __syncthreads();   // chunk staged

        // S^T = K Q^T : D[key][q], lane: q = wq0+cl (col), keys ki*16+g*4+r (rows)
        f32x4 s[8];
#pragma unroll
        for (int ki = 0; ki < 8; ++ki) s[ki] = fzero4();
#pragma unroll
        for (int ki = 0; ki < 8; ++ki) {
            int key = ki * 16 + cl;
#pragma unroll
            for (int kk = 0; kk < 2; ++kk) {
                bf16x8 kf = *(const bf16x8*)(ldsK + ((key * 128 + (kk * 32 + g * 8) * 2) ^ ((key & 7) << 4)));
                s[ki] = MFMA16(kf, qf[kk], s[ki]);
            }
        }

        // p = exp(s/8); accumulate per-lane partial row-sum; pack 4 keys -> b64 P write
        const int q = wq0 + cl;
#pragma unroll
        for (int ki = 0; ki < 8; ++ki) {
            float p0 = __expf(s[ki][0] * 0.125f);
            float p1 = __expf(s[ki][1] * 0.125f);
            float p2 = __expf(s[ki][2] * 0.125f);
            float p3 = __expf(s[ki][3] * 0.125f);
            lsum += (p0 + p1) + (p2 + p3);
            uint2 pk; pk.x = cvtpk(p0, p1); pk.y = cvtpk(p2, p3);
            *(uint2*)(ldsP + ((q * 256 + (ki * 16 + g * 4) * 2) ^ ((q & 7) << 4))) = pk;
        }

        // O += P V  (A = own-wave P rows, B = V^T)
#pragma unroll
        for (int kk2 = 0; kk2 < 4; ++kk2) {
            bf16x8 pf = *(const bf16x8*)(ldsP + ((q * 256 + (kk2 * 32 + g * 8) * 2) ^ ((q & 7) << 4)));
#pragma unroll
            for (int ni = 0; ni < 4; ++ni) {
                int d = ni * 16 + cl;
                bf16x8 vf = *(const bf16x8*)(ldsV + ((d * 256 + (kk2 * 32 + g * 8) * 2) ^ ((d & 7) << 4)));
                o[ni] = MFMA16(pf, vf, o[ni]);
            }
        }
    }

    // finalize row sums: reduce over the 4 g-lanes holding the same q
    float ls = lsum;
    ls += __shfl_xor(ls, 16, 64);
    ls += __shfl_xor(ls, 32, 64);
    if (t < 7) ls += 128.0f * (float)(7 - t);   // padded lags: exp(0)=1 each
    if (g == 0) lsumBuf[wq0 + cl] = ls;
    __syncthreads();   // lsum visible; all waves done with ldsK/ldsV

    // agg = O/lsum -> ldsK as h rows [128 q][64 c] bf16 (swizzled)
    float inv[4];
#pragma unroll
    for (int r = 0; r < 4; ++r) inv[r] = 1.0f / lsumBuf[wq0 + g * 4 + r];
#pragma unroll
    for (int ni = 0; ni < 4; ++ni)
#pragma unroll
        for (int r = 0; r < 4; ++r) {
            int qq = wq0 + g * 4 + r;
            int d = ni * 16 + cl;
            *(unsigned short*)(ldsK + ((qq * 128 + d * 2) ^ ((qq & 7) << 4))) =
                f2bf(o[ni][r] * inv[r]);
        }

    // stage Wo^T [64 dout][128 c] bf16 into ldsV (coalesced reads)
    for (int i = tid; i < 8192; i += 512) {
        int c = i >> 6, d = i & 63;
        *(unsigned short*)(ldsV + ((d * 256 + c * 2) ^ ((d & 7) << 4))) = f2bf(Wo[c * 64 + d]);
    }
    __syncthreads();

    // out = relu([Q | agg] @ Wo + bo)
    f32x4 h2[4];
#pragma unroll
    for (int ni = 0; ni < 4; ++ni) h2[ni] = fzero4();
#pragma unroll
    for (int kk = 0; kk < 4; ++kk) {
        bf16x8 ha;
        if (kk < 2) {
            ha = qf[kk];
        } else {
            int qq = wq0 + cl;
            ha = *(const bf16x8*)(ldsK + ((qq * 128 + ((kk - 2) * 32 + g * 8) * 2) ^ ((qq & 7) << 4)));
        }
#pragma unroll
        for (int ni = 0; ni < 4; ++ni) {
            int dd = ni * 16 + cl;
            bf16x8 wb = *(const bf16x8*)(ldsV + ((dd * 256 + (kk * 32 + g * 8) * 2) ^ ((dd & 7) << 4)));
            h2[ni] = MFMA16(ha, wb, h2[ni]);
        }
    }
#pragma unroll
    for (int ni = 0; ni < 4; ++ni) {
        float b = bo[ni * 16 + cl];
#pragma unroll
        for (int r = 0; r < 4; ++r) {
            float v = h2[ni][r] + b;
            v = v > 0.f ? v : 0.f;
            Out[((size_t)bt * 128 + wq0 + g * 4 + r) * 64 + ni * 16 + cl] = v;
        }
    }
}

// ---------------------------------------------------------------------------
extern "C" void kernel_launch(void* const* d_in, const int* in_sizes, int n_in,
                              void* d_out, int out_size, void* d_ws, size_t ws_size,
                              hipStream_t stream) {
    const float* X  = (const float*)d_in[0];
    const float* Wq = (const float*)d_in[1];
    const float* bq = (const float*)d_in[2];
    const float* Wk = (const float*)d_in[3];
    const float* bk = (const float*)d_in[4];
    const float* Wv = (const float*)d_in[5];
    const float* bv = (const float*)d_in[6];
    const float* Wo = (const float*)d_in[7];
    const float* bo = (const float*)d_in[8];
    float* Out = (float*)d_out;

    unsigned short* Qw = (unsigned short*)d_ws;            // 3 x 8 MB bf16
    unsigned short* Kw = Qw + (size_t)65536 * 64;
    unsigned short* Vw = Kw + (size_t)65536 * 64;          // V^T per (b,t): [64][128]

    hipLaunchKernelGGL(qkv_kernel, dim3(1024), dim3(256), 0, stream,
                       X, Wq, bq, Wk, bk, Wv, bv, Qw, Kw, Vw);
    hipLaunchKernelGGL(attn_kernel, dim3(512), dim3(512), 0, stream,
                       Qw, Kw, Vw, Wo, bo, Out);
}